// Round 8
// baseline (517.953 us; speedup 1.0000x reference)
//
#include <hip/hip_runtime.h>
#include <hip/hip_bf16.h>
#include <hip/hip_fp16.h>

#define F_IN 128
#define F_E  32
#define DH   128   // D*H
#define HD   32    // D

using bf16x8 = __attribute__((ext_vector_type(8))) short;
using f32x4  = __attribute__((ext_vector_type(4))) float;

__device__ __forceinline__ unsigned short f2bf(float f) {
    unsigned int x = __float_as_uint(f);
    unsigned int r = (x + 0x7fffu + ((x >> 16) & 1u)) >> 16;   // RNE
    return (unsigned short)r;
}

// ---- prep: We_fold[f][h] = sum_d W_edge[f][h*32+d] * attn[h][64+d]  (32x4)
__global__ void prep_kernel(const float* __restrict__ W_edge,
                            const float* __restrict__ attn,
                            float* __restrict__ wefold) {
    int t = threadIdx.x;            // 128 threads
    int f = t >> 2, h = t & 3;
    float s = 0.f;
#pragma unroll
    for (int d = 0; d < 32; ++d)
        s += W_edge[f * DH + h * HD + d] * attn[h * 96 + 64 + d];
    wefold[f * 4 + h] = s;
}

// ---- node projection via MFMA (bf16 in, fp32 accum) + per-head src scores.
// Tile: 128 rows x 128 cols x K=128 per 256-thread block (4 waves).
// LDS XOR-swizzled (byte ^= (row&7)<<4). C layout (m89): col=lane&15,
// row=(lane>>4)*4+reg.
__global__ __launch_bounds__(256, 2)
void node_proj_kernel(const float* __restrict__ x, const float* __restrict__ Wn,
                      const float* __restrict__ attn,
                      unsigned short* __restrict__ proj_bf,
                      float* __restrict__ s_src, int N) {
    __shared__ __align__(16) unsigned char xb[32768];
    __shared__ __align__(16) unsigned char wb[32768];
    const int t    = threadIdx.x;
    const int n0   = blockIdx.x * 128;
    const int lane = t & 63;
    const int wid  = t >> 6;
    const int lg   = lane >> 4;       // lane group 0..3 (k-subrange)
    const int lm   = lane & 15;

    // ---- stage x tile (fp32 -> bf16), swizzled; 16 float4 per thread
    {
        const float4* x4 = (const float4*)x;
#pragma unroll
        for (int j = 0; j < 16; ++j) {
            int idx = t + j * 256;          // 0..4095
            int n   = idx >> 5;             // row 0..127
            int kq  = idx & 31;             // float4 index along K
            float4 v = make_float4(0.f, 0.f, 0.f, 0.f);
            if (n0 + n < N) v = x4[(size_t)(n0 + n) * 32 + kq];
            unsigned int lo = (unsigned int)f2bf(v.x) | ((unsigned int)f2bf(v.y) << 16);
            unsigned int hi = (unsigned int)f2bf(v.z) | ((unsigned int)f2bf(v.w) << 16);
            int byte = (n * 256 + kq * 8) ^ ((n & 7) << 4);
            *(uint2*)&xb[byte] = make_uint2(lo, hi);
        }
    }
    // ---- stage W^T (fp32 -> bf16): thread covers col c, 64 k's
    {
        const int c  = t & 127;
        const int kg = t >> 7;
#pragma unroll
        for (int jb = 0; jb < 8; ++jb) {
            int k0 = kg * 64 + jb * 8;
            unsigned int p0, p1, p2, p3;
            {
                float a0 = Wn[(size_t)(k0 + 0) * 128 + c];
                float a1 = Wn[(size_t)(k0 + 1) * 128 + c];
                float a2 = Wn[(size_t)(k0 + 2) * 128 + c];
                float a3 = Wn[(size_t)(k0 + 3) * 128 + c];
                float a4 = Wn[(size_t)(k0 + 4) * 128 + c];
                float a5 = Wn[(size_t)(k0 + 5) * 128 + c];
                float a6 = Wn[(size_t)(k0 + 6) * 128 + c];
                float a7 = Wn[(size_t)(k0 + 7) * 128 + c];
                p0 = (unsigned int)f2bf(a0) | ((unsigned int)f2bf(a1) << 16);
                p1 = (unsigned int)f2bf(a2) | ((unsigned int)f2bf(a3) << 16);
                p2 = (unsigned int)f2bf(a4) | ((unsigned int)f2bf(a5) << 16);
                p3 = (unsigned int)f2bf(a6) | ((unsigned int)f2bf(a7) << 16);
            }
            int byte = (c * 256 + k0 * 2) ^ ((c & 7) << 4);
            *(uint4*)&wb[byte] = make_uint4(p0, p1, p2, p3);
        }
    }
    __syncthreads();

    // ---- MFMA main: wave computes 32 rows x 128 cols
    const int wrow = wid * 32;
    f32x4 acc[2][8];
#pragma unroll
    for (int fm = 0; fm < 2; ++fm)
#pragma unroll
        for (int fn = 0; fn < 8; ++fn)
#pragma unroll
            for (int q = 0; q < 4; ++q) acc[fm][fn][q] = 0.f;

#pragma unroll
    for (int ks = 0; ks < 4; ++ks) {
        bf16x8 bfr[8];
#pragma unroll
        for (int fn = 0; fn < 8; ++fn) {
            int col  = fn * 16 + lm;
            int byte = (col * 256 + ks * 64 + lg * 16) ^ ((col & 7) << 4);
            bfr[fn] = *(const bf16x8*)&wb[byte];
        }
#pragma unroll
        for (int fm = 0; fm < 2; ++fm) {
            int row  = wrow + fm * 16 + lm;
            int byte = (row * 256 + ks * 64 + lg * 16) ^ ((row & 7) << 4);
            bf16x8 afr = *(const bf16x8*)&xb[byte];
#pragma unroll
            for (int fn = 0; fn < 8; ++fn)
                acc[fm][fn] = __builtin_amdgcn_mfma_f32_16x16x32_bf16(
                    afr, bfr[fn], acc[fm][fn], 0, 0, 0);
        }
    }

    // ---- s_src epilogue
    float asv[8];
#pragma unroll
    for (int fn = 0; fn < 8; ++fn)
        asv[fn] = attn[(fn >> 1) * 96 + (fn & 1) * 16 + lm];
#pragma unroll
    for (int fm = 0; fm < 2; ++fm)
#pragma unroll
        for (int j = 0; j < 4; ++j) {
            int row = n0 + wrow + fm * 16 + lg * 4 + j;
#pragma unroll
            for (int h = 0; h < 4; ++h) {
                float ps = fmaf(acc[fm][2 * h][j], asv[2 * h],
                                acc[fm][2 * h + 1][j] * asv[2 * h + 1]);
                ps += __shfl_xor(ps, 1);
                ps += __shfl_xor(ps, 2);
                ps += __shfl_xor(ps, 4);
                ps += __shfl_xor(ps, 8);
                if (lm == h && row < N) s_src[row * 4 + h] = ps;
            }
        }

    // ---- proj epilogue via LDS transpose, coalesced uint4 stores
    __syncthreads();
#pragma unroll
    for (int fm = 0; fm < 2; ++fm)
#pragma unroll
        for (int fn = 0; fn < 8; ++fn)
#pragma unroll
            for (int j = 0; j < 4; ++j) {
                int r = wrow + fm * 16 + lg * 4 + j;
                int c = fn * 16 + lm;
                *(unsigned short*)&xb[r * 256 + c * 2] = f2bf(acc[fm][fn][j]);
            }
    __syncthreads();
#pragma unroll
    for (int j = 0; j < 8; ++j) {
        int idx = t + j * 256;              // 0..2047 (16B chunks)
        int row = idx >> 4;
        if (n0 + row < N) {
            uint4 v = *(const uint4*)&xb[idx * 16];
            *(uint4*)&proj_bf[(size_t)(n0 + row) * 128 + (idx & 15) * 8] = v;
        }
    }
}

// ---- edge prep: 2 edges per thread for memory-level parallelism.
// 16 independent float4 ef loads + 2 s_src gathers + 2 rank atomics in
// flight per thread. Stores stay coalesced (two contiguous 256-rec ranges).
__global__ __launch_bounds__(256)
void edgeprep_kernel(const float* __restrict__ ef, const int* __restrict__ eidx,
                     const float* __restrict__ wefold,
                     const float* __restrict__ s_src,
                     int* __restrict__ cnt, uint4* __restrict__ rec_e, int E) {
    __shared__ float wf[128];
    const int t = threadIdx.x;
    if (t < 128) wf[t] = wefold[t];
    __syncthreads();

    const int e0 = blockIdx.x * 512 + t;
    const int e1 = e0 + 256;
    const bool v0 = e0 < E, v1 = e1 < E;
    const int ce0 = v0 ? e0 : 0, ce1 = v1 ? e1 : 0;

    int2 sd0 = ((const int2*)eidx)[ce0];
    int2 sd1 = ((const int2*)eidx)[ce1];
    // fire rank atomics early -- independent of the ef dot product
    int r0 = v0 ? atomicAdd(&cnt[sd0.y], 1) : 0;
    int r1 = v1 ? atomicAdd(&cnt[sd1.y], 1) : 0;
    float4 a0 = *(const float4*)&s_src[sd0.x * 4];   // random 16B, L2-resident
    float4 a1 = *(const float4*)&s_src[sd1.x * 4];

    float p00 = 0.f, p01 = 0.f, p02 = 0.f, p03 = 0.f;
    float p10 = 0.f, p11 = 0.f, p12 = 0.f, p13 = 0.f;
#pragma unroll
    for (int f4 = 0; f4 < 8; ++f4) {
        float4 u = *(const float4*)&ef[(size_t)ce0 * F_E + f4 * 4];
        float4 w = *(const float4*)&ef[(size_t)ce1 * F_E + f4 * 4];
        float uu[4] = {u.x, u.y, u.z, u.w};
        float ww[4] = {w.x, w.y, w.z, w.w};
#pragma unroll
        for (int q = 0; q < 4; ++q) {
            float4 wv = *(const float4*)&wf[(f4 * 4 + q) * 4];
            p00 = fmaf(uu[q], wv.x, p00);
            p01 = fmaf(uu[q], wv.y, p01);
            p02 = fmaf(uu[q], wv.z, p02);
            p03 = fmaf(uu[q], wv.w, p03);
            p10 = fmaf(ww[q], wv.x, p10);
            p11 = fmaf(ww[q], wv.y, p11);
            p12 = fmaf(ww[q], wv.z, p12);
            p13 = fmaf(ww[q], wv.w, p13);
        }
    }
    // no segment-max shift, no s_dst: |logit| small; softmax ratio unchanged
    if (v0) {
        float w0 = __expf(a0.x + p00), w1 = __expf(a0.y + p01);
        float w2 = __expf(a0.z + p02), w3 = __expf(a0.w + p03);
        unsigned int u0 = __half_as_ushort(__float2half_rn(w0));
        unsigned int u1 = __half_as_ushort(__float2half_rn(w1));
        unsigned int u2 = __half_as_ushort(__float2half_rn(w2));
        unsigned int u3 = __half_as_ushort(__float2half_rn(w3));
        uint4 R;
        R.x = (unsigned int)sd0.x;
        R.y = u0 | (u1 << 16);
        R.z = u2 | (u3 << 16);
        R.w = ((unsigned int)sd0.y << 15) | (unsigned int)r0;
        rec_e[e0] = R;
    }
    if (v1) {
        float w0 = __expf(a1.x + p10), w1 = __expf(a1.y + p11);
        float w2 = __expf(a1.z + p12), w3 = __expf(a1.w + p13);
        unsigned int u0 = __half_as_ushort(__float2half_rn(w0));
        unsigned int u1 = __half_as_ushort(__float2half_rn(w1));
        unsigned int u2 = __half_as_ushort(__float2half_rn(w2));
        unsigned int u3 = __half_as_ushort(__float2half_rn(w3));
        uint4 R;
        R.x = (unsigned int)sd1.x;
        R.y = u0 | (u1 << 16);
        R.z = u2 | (u3 << 16);
        R.w = ((unsigned int)sd1.y << 15) | (unsigned int)r1;
        rec_e[e1] = R;
    }
}

// ---- scan step 1: per-block exclusive scan + block sums
__global__ __launch_bounds__(256)
void scan1_kernel(const int* __restrict__ cnt, int* __restrict__ cursor,
                  int* __restrict__ bsum, int N) {
    __shared__ int s[256];
    const int t = threadIdx.x;
    int i = blockIdx.x * 256 + t;
    int v = (i < N) ? cnt[i] : 0;
    s[t] = v;
    __syncthreads();
#pragma unroll
    for (int d = 1; d < 256; d <<= 1) {
        int x = (t >= d) ? s[t - d] : 0;
        __syncthreads();
        s[t] += x;
        __syncthreads();
    }
    if (i < N) cursor[i] = s[t] - v;
    if (t == 255) bsum[blockIdx.x] = s[255];
}

// ---- scan step 2: exclusive scan of block sums (nb <= 512)
__global__ __launch_bounds__(512)
void scan2_kernel(int* __restrict__ bsum, int nb) {
    __shared__ int s[512];
    const int t = threadIdx.x;
    int v = (t < nb) ? bsum[t] : 0;
    s[t] = v;
    __syncthreads();
#pragma unroll
    for (int d = 1; d < 512; d <<= 1) {
        int x = (t >= d) ? s[t - d] : 0;
        __syncthreads();
        s[t] += x;
        __syncthreads();
    }
    if (t < nb) bsum[t] = s[t] - v;
}

// ---- scatter-lite: permute edge-order records into CSR order.
// pos = cursor[d] + bsum[d>>8] + rank  (scan3 folded in; bsum is L2-hot 1.5KB)
__global__ __launch_bounds__(256)
void scatter_kernel(const uint4* __restrict__ rec_e,
                    const int* __restrict__ cursor,
                    const int* __restrict__ bsum,
                    uint4* __restrict__ rec, int E) {
    const int e = blockIdx.x * 256 + threadIdx.x;
    if (e >= E) return;
    uint4 R = rec_e[e];
    int d = (int)(R.w >> 15);
    int r = (int)(R.w & 32767u);
    int pos = cursor[d] + bsum[d >> 8] + r;
    rec[pos] = R;
}

// ---- gather: one wave per dst node; 3-stage software pipeline.
// Per iteration: issue rec loads for batch k+2, issue proj loads for batch
// k+1 (addresses SEL'd last iter), FMA batch k (pv had a FULL iteration to
// land -> counted vmcnt), SEL batch k+2 (waits only the rec loads; proj
// loads stay in flight). Lanes 0-31 even edges / 32-63 odd edges; uint2
// dual-row proj reads (512B/wave/instr). ALL state in NAMED registers
// (rule #20). Tail branchless: rec has 256B slack; pads get src=0/w=0.
__global__ __launch_bounds__(256)
void gather_kernel(const int* __restrict__ cursor, const int* __restrict__ bsum,
                   const uint4* __restrict__ rec,
                   const unsigned int* __restrict__ proj_bf,
                   unsigned int* __restrict__ numer_bf, int N, int E) {
    const int t    = threadIdx.x;
    const int lane = t & 63;
    const int n    = blockIdx.x * 4 + (t >> 6);
    if (n >= N) return;

    int start = cursor[n] + bsum[n >> 8];
    int end   = (n == N - 1) ? E : (cursor[n + 1] + bsum[(n + 1) >> 8]);
    start = __builtin_amdgcn_readfirstlane(start);
    end   = __builtin_amdgcn_readfirstlane(end);

    const int  hf  = lane >> 5;      // 0: even edges, 1: odd edges
    const int  col = lane & 31;      // uint2 pair index within the 256B row
    const int  h   = col >> 3;       // head for bf16 cols 4*col..4*col+3
    const bool hiw = (h & 1) != 0;
    const bool low = (h < 2);

    float4 acc = make_float4(0.f, 0.f, 0.f, 0.f);
    float dsum = 0.f;

    auto SEL = [&](uint4 qa, uint4 qb, int j, int cc,
                   unsigned int& sx, unsigned int& wp) {
        unsigned int s  = hf ? qb.x : qa.x;
        unsigned int py = hf ? qb.y : qa.y;
        unsigned int pz = hf ? qb.z : qa.z;
        bool v = (2 * j + hf) < cc;
        sx = v ? s : 0u;
        unsigned int pk = low ? py : pz;
        wp = v ? pk : 0u;
    };
    auto FMA = [&](unsigned int wp, uint2 pv) {
        unsigned short uw = hiw ? (unsigned short)(wp >> 16)
                                : (unsigned short)(wp & 0xffffu);
        float w = __half2float(__ushort_as_half(uw));
        dsum += w;
        acc.x = fmaf(w, __uint_as_float(pv.x << 16), acc.x);
        acc.y = fmaf(w, __uint_as_float(pv.x & 0xffff0000u), acc.y);
        acc.z = fmaf(w, __uint_as_float(pv.y << 16), acc.z);
        acc.w = fmaf(w, __uint_as_float(pv.y & 0xffff0000u), acc.w);
    };

    int rem = end - start;
    int cA  = rem < 8 ? rem : 8;

    // prologue: batch A recs + SEL + proj issue
    unsigned int sxA0, sxA1, sxA2, sxA3, wpA0, wpA1, wpA2, wpA3;
    {
        uint4 q0 = rec[start + 0], q1 = rec[start + 1];
        uint4 q2 = rec[start + 2], q3 = rec[start + 3];
        uint4 q4 = rec[start + 4], q5 = rec[start + 5];
        uint4 q6 = rec[start + 6], q7 = rec[start + 7];
        SEL(q0, q1, 0, cA, sxA0, wpA0);
        SEL(q2, q3, 1, cA, sxA1, wpA1);
        SEL(q4, q5, 2, cA, sxA2, wpA2);
        SEL(q6, q7, 3, cA, sxA3, wpA3);
    }
    uint2 pvA0 = *(const uint2*)&proj_bf[(size_t)sxA0 * 64 + col * 2];
    uint2 pvA1 = *(const uint2*)&proj_bf[(size_t)sxA1 * 64 + col * 2];
    uint2 pvA2 = *(const uint2*)&proj_bf[(size_t)sxA2 * 64 + col * 2];
    uint2 pvA3 = *(const uint2*)&proj_bf[(size_t)sxA3 * 64 + col * 2];

    // prologue: batch B recs + SEL (proj for B issued inside the loop)
    int iB   = start + cA;
    int remB = rem - cA;
    int cB   = remB < 8 ? remB : 8;
    unsigned int sxB0, sxB1, sxB2, sxB3, wpB0, wpB1, wpB2, wpB3;
    {
        uint4 q0 = rec[iB + 0], q1 = rec[iB + 1];
        uint4 q2 = rec[iB + 2], q3 = rec[iB + 3];
        uint4 q4 = rec[iB + 4], q5 = rec[iB + 5];
        uint4 q6 = rec[iB + 6], q7 = rec[iB + 7];
        SEL(q0, q1, 0, cB, sxB0, wpB0);
        SEL(q2, q3, 1, cB, sxB1, wpB1);
        SEL(q4, q5, 2, cB, sxB2, wpB2);
        SEL(q6, q7, 3, cB, sxB3, wpB3);
    }
    int iC   = iB + cB;
    int remC = remB - cB;

    while (cA > 0) {
        const int cC = remC < 8 ? remC : 8;
        // stage 1: rec loads for batch k+2 (oldest of this iteration)
        uint4 q0 = rec[iC + 0], q1 = rec[iC + 1];
        uint4 q2 = rec[iC + 2], q3 = rec[iC + 3];
        uint4 q4 = rec[iC + 4], q5 = rec[iC + 5];
        uint4 q6 = rec[iC + 6], q7 = rec[iC + 7];
        // stage 2: proj loads for batch k+1 (addresses ready since last iter)
        uint2 pvB0 = *(const uint2*)&proj_bf[(size_t)sxB0 * 64 + col * 2];
        uint2 pvB1 = *(const uint2*)&proj_bf[(size_t)sxB1 * 64 + col * 2];
        uint2 pvB2 = *(const uint2*)&proj_bf[(size_t)sxB2 * 64 + col * 2];
        uint2 pvB3 = *(const uint2*)&proj_bf[(size_t)sxB3 * 64 + col * 2];
        // stage 3: FMA batch k -- pv issued a full iteration ago
        FMA(wpA0, pvA0);
        FMA(wpA1, pvA1);
        FMA(wpA2, pvA2);
        FMA(wpA3, pvA3);
        // stage 4: SEL batch k+2 (waits rec loads only; pvB stays in flight)
        unsigned int sxC0, sxC1, sxC2, sxC3, wpC0, wpC1, wpC2, wpC3;
        SEL(q0, q1, 0, cC, sxC0, wpC0);
        SEL(q2, q3, 1, cC, sxC1, wpC1);
        SEL(q4, q5, 2, cC, sxC2, wpC2);
        SEL(q6, q7, 3, cC, sxC3, wpC3);
        // rotate named state
        pvA0 = pvB0; pvA1 = pvB1; pvA2 = pvB2; pvA3 = pvB3;
        wpA0 = wpB0; wpA1 = wpB1; wpA2 = wpB2; wpA3 = wpB3;
        sxB0 = sxC0; sxB1 = sxC1; sxB2 = sxC2; sxB3 = sxC3;
        wpB0 = wpC0; wpB1 = wpC1; wpB2 = wpC2; wpB3 = wpC3;
        iC += cC; remC -= cC;
        cA = cB; cB = cC;
    }

    dsum  += __shfl_xor(dsum, 32);
    acc.x += __shfl_xor(acc.x, 32);
    acc.y += __shfl_xor(acc.y, 32);
    acc.z += __shfl_xor(acc.z, 32);
    acc.w += __shfl_xor(acc.w, 32);

    if (hf == 0) {
        float r = 1.f / (dsum + 1e-8f);
        uint2 p;
        p.x = (unsigned int)f2bf(acc.x * r) | ((unsigned int)f2bf(acc.y * r) << 16);
        p.y = (unsigned int)f2bf(acc.z * r) | ((unsigned int)f2bf(acc.w * r) << 16);
        *(uint2*)&numer_bf[(size_t)n * 64 + col * 2] = p;  // 256B/wave contiguous
    }
}

// ---- epilogue: out = gelu(agg @ W_out + b_out); agg (bf16) already normalized
__global__ __launch_bounds__(256, 2)
void out_kernel(const unsigned int* __restrict__ numer_bf,
                const float* __restrict__ Wout, const float* __restrict__ bout,
                float* __restrict__ out, int N) {
    __shared__ float wsh[128 * 32];
    __shared__ float bsh[32];
    const int t = threadIdx.x;
    for (int i = t; i < 4096; i += 256) wsh[i] = Wout[i];
    if (t < 32) bsh[t] = bout[t];
    __syncthreads();

    int n = blockIdx.x * 256 + t;
    if (n >= N) return;

    float acc[32];
#pragma unroll
    for (int j = 0; j < 32; ++j) acc[j] = 0.f;

    for (int kg = 0; kg < 16; ++kg) {
        uint4 v = *(const uint4*)&numer_bf[(size_t)n * 64 + kg * 4];
        unsigned int vv[4] = {v.x, v.y, v.z, v.w};
#pragma unroll
        for (int q = 0; q < 4; ++q) {
            int k = kg * 8 + q * 2;
            float a0 = __uint_as_float(vv[q] << 16);
            float a1 = __uint_as_float(vv[q] & 0xffff0000u);
#pragma unroll
            for (int j = 0; j < 32; j += 4) {
                float4 w0 = *(const float4*)&wsh[k * 32 + j];
                float4 w1 = *(const float4*)&wsh[(k + 1) * 32 + j];
                acc[j + 0] = fmaf(a0, w0.x, fmaf(a1, w1.x, acc[j + 0]));
                acc[j + 1] = fmaf(a0, w0.y, fmaf(a1, w1.y, acc[j + 1]));
                acc[j + 2] = fmaf(a0, w0.z, fmaf(a1, w1.z, acc[j + 2]));
                acc[j + 3] = fmaf(a0, w0.w, fmaf(a1, w1.w, acc[j + 3]));
            }
        }
    }
#pragma unroll
    for (int j = 0; j < 32; ++j) {
        float z = acc[j] + bsh[j];
        acc[j] = 0.5f * z * (1.f + erff(z * 0.70710678118654752f));
    }
#pragma unroll
    for (int j = 0; j < 32; j += 4)
        *(float4*)&out[(size_t)n * 32 + j] = make_float4(acc[j], acc[j+1], acc[j+2], acc[j+3]);
}

extern "C" void kernel_launch(void* const* d_in, const int* in_sizes, int n_in,
                              void* d_out, int out_size, void* d_ws, size_t ws_size,
                              hipStream_t stream) {
    const float* x    = (const float*)d_in[0];
    const int*   eidx = (const int*)d_in[1];
    const float* ef   = (const float*)d_in[2];
    const float* Wn   = (const float*)d_in[3];
    const float* We   = (const float*)d_in[4];
    const float* attn = (const float*)d_in[5];
    const float* Wout = (const float*)d_in[6];
    const float* bout = (const float*)d_in[7];
    float* out = (float*)d_out;

    const int N = in_sizes[0] / F_IN;
    const int E = in_sizes[1] / 2;
    const int NB = (N + 255) / 256;          // scan blocks; must be <= 512

    char* ws = (char*)d_ws;
    size_t off = 0;
    auto alloc = [&](size_t bytes) {
        void* p = ws + off;
        off = (off + bytes + 255) & ~(size_t)255;
        return p;
    };
    int*   cnt     = (int*)  alloc((size_t)N * 4);           // zeroed
    size_t zero_bytes = off;                                 // 400 KB
    int*   cursor  = (int*)  alloc((size_t)N * 4);
    int*   bsum    = (int*)  alloc(512 * 4);
    float* wefold  = (float*)alloc(512);
    float* s_src   = (float*)alloc((size_t)N * 4 * 4);
    unsigned short* proj_bf = (unsigned short*)alloc((size_t)N * DH * 2);  // 25.6 MB
    size_t numer_bytes = (size_t)N * 64 * 4;                 // 25.6 MB
    size_t rece_bytes  = (size_t)E * 16;                     // 25.6 MB
    unsigned int* numer_bf = (unsigned int*)alloc(numer_bytes > rece_bytes ?
                                                  numer_bytes : rece_bytes);
    uint4* rec_e   = (uint4*)numer_bf;       // alias: rec_e dead before gather writes
    uint4* rec     = (uint4*)alloc((size_t)E * 16 + 256);    // +256B slack (2-batch lookahead)

    hipMemsetAsync(d_ws, 0, zero_bytes, stream);
    hipLaunchKernelGGL(prep_kernel, dim3(1), dim3(128), 0, stream, We, attn, wefold);
    hipLaunchKernelGGL(node_proj_kernel, dim3((N + 127) / 128), dim3(256), 0, stream,
                       x, Wn, attn, proj_bf, s_src, N);
    hipLaunchKernelGGL(edgeprep_kernel, dim3((E + 511) / 512), dim3(256), 0, stream,
                       ef, eidx, wefold, s_src, cnt, rec_e, E);
    hipLaunchKernelGGL(scan1_kernel, dim3(NB), dim3(256), 0, stream, cnt, cursor, bsum, N);
    hipLaunchKernelGGL(scan2_kernel, dim3(1), dim3(512), 0, stream, bsum, NB);
    hipLaunchKernelGGL(scatter_kernel, dim3((E + 255) / 256), dim3(256), 0, stream,
                       rec_e, cursor, bsum, rec, E);
    hipLaunchKernelGGL(gather_kernel, dim3((N + 3) / 4), dim3(256), 0, stream,
                       cursor, bsum, rec, (const unsigned int*)proj_bf, numer_bf, N, E);
    hipLaunchKernelGGL(out_kernel, dim3((N + 255) / 256), dim3(256), 0, stream,
                       numer_bf, Wout, bout, out, N);
}